// Round 1
// baseline (95.027 us; speedup 1.0000x reference)
//
#include <hip/hip_runtime.h>
#include <math.h>

#define TMAX 6336   // S[T] == 0 for T >= 6208; clamp into zero rows
#define B2N  16384

// ---------------------------------------------------------------------------
// Kernel 1: build S[T][r][h] = sum_k w(T,k) * W1[(r*128+k)*32 + h]
//   w(T,k) = max(0, 1 - 0.5*|g0 + k/8192|),  g0 = (T-64)/2048 - 1
// Grid: (TMAX/64, 8), block 256.  LDS: W1 slab (16 KB) + w matrix (32 KB).
// ---------------------------------------------------------------------------
__global__ __launch_bounds__(256) void build_S(const float* __restrict__ W1,
                                               float* __restrict__ S) {
  const int r  = blockIdx.y;
  const int T0 = blockIdx.x * 64;
  __shared__ float W1s[128 * 32];   // [k][h]
  __shared__ float wls[128 * 64];   // [k][T_local]
  const int t = threadIdx.x;

  // stage W1 slab for this r (4096 floats = 1024 float4)
  const float4* src = (const float4*)(W1 + r * 128 * 32);
  float4* dst = (float4*)W1s;
#pragma unroll
  for (int i = 0; i < 4; i++) dst[t + i * 256] = src[t + i * 256];

  // compute triangle weights w for all (k, T_local)
  for (int e = t; e < 128 * 64; e += 256) {
    const int k  = e >> 6;
    const int Tl = e & 63;
    const float g0 = (float)(T0 + Tl - 64) * (1.0f / 2048.0f) - 1.0f;
    const float gx = g0 + (float)k * (1.0f / 8192.0f);
    wls[e] = fmaxf(0.0f, fmaf(-0.5f, fabsf(gx), 1.0f));
  }
  __syncthreads();

  const int h  = t & 31;
  const int tb = t >> 5;  // handles T_local = tb*8 + j
  float acc[8] = {0.f, 0.f, 0.f, 0.f, 0.f, 0.f, 0.f, 0.f};
#pragma unroll 4
  for (int k = 0; k < 128; k++) {
    const float wv = W1s[k * 32 + h];                       // broadcast per k
    const float4* wp = (const float4*)(&wls[k * 64 + tb * 8]);
    const float4 w0 = wp[0];
    const float4 w1 = wp[1];
    acc[0] = fmaf(w0.x, wv, acc[0]);
    acc[1] = fmaf(w0.y, wv, acc[1]);
    acc[2] = fmaf(w0.z, wv, acc[2]);
    acc[3] = fmaf(w0.w, wv, acc[3]);
    acc[4] = fmaf(w1.x, wv, acc[4]);
    acc[5] = fmaf(w1.y, wv, acc[5]);
    acc[6] = fmaf(w1.z, wv, acc[6]);
    acc[7] = fmaf(w1.w, wv, acc[7]);
  }
#pragma unroll
  for (int j = 0; j < 8; j++) {
    const int T = T0 + tb * 8 + j;
    S[(((T << 3) + r) << 5) + h] = acc[j];
  }
}

// ---------------------------------------------------------------------------
// Kernel 2: per-sample distances -> T -> gather S rows -> tiny MLP head
// Grid: 256 blocks x 256 threads, one thread per (b, s).
// ---------------------------------------------------------------------------
__global__ __launch_bounds__(256) void tof_main(
    const float* __restrict__ recordings, const float* __restrict__ sloc,
    const float* __restrict__ emit, const float* __restrict__ rloc,
    const float* __restrict__ b1v, const float* __restrict__ W2,
    const float* __restrict__ b2v, const float* __restrict__ S,
    float* __restrict__ out) {
  __shared__ float vy[8];
  __shared__ float em[3];
  __shared__ float rl[24];
  __shared__ float b1s[32];
  __shared__ float W2s[32];
  __shared__ float b2s;
  const int t = threadIdx.x;
  const int sid = blockIdx.x * 256 + t;
  const int b = sid >> 14;  // /16384; 64 blocks per b -> uniform within block

  if (t < 8) {
    const float* rp = recordings + ((b << 3) + t) * 4096;
    vy[t] = 0.5f * (rp[2047] + rp[2048]);
  }
  if (t < 3) em[t] = emit[t];
  if (t >= 32 && t < 56) rl[t - 32] = rloc[t - 32];
  if (t >= 64 && t < 96) b1s[t - 64] = b1v[t - 64];
  if (t >= 96 && t < 128) W2s[t - 96] = W2[t - 96];
  if (t == 128) b2s = b2v[0];
  __syncthreads();

  const float x = sloc[sid * 3 + 0];
  const float y = sloc[sid * 3 + 1];
  const float z = sloc[sid * 3 + 2];
  const float ex = x - em[0], ey = y - em[1], ez = z - em[2];
  const float de = sqrtf(ex * ex + ey * ey + ez * ez);

  float acc[32];
#pragma unroll
  for (int h = 0; h < 32; h++) acc[h] = 0.f;

#pragma unroll
  for (int r = 0; r < 8; r++) {
    const float rx = x - rl[r * 3 + 0];
    const float ry = y - rl[r * 3 + 1];
    const float rz = z - rl[r * 3 + 2];
    const float dr = sqrtf(rx * rx + ry * ry + rz * rz);
    const float ts = rintf(((de + dr) / 343.0f) * 96000.0f);
    int T = (int)ts;
    T = min(max(T, 0), TMAX - 1);
    const float4* Srow = (const float4*)(S + (((T << 3) + r) << 5));
    const float vr = vy[r];
#pragma unroll
    for (int q = 0; q < 8; q++) {
      const float4 v = Srow[q];
      acc[4 * q + 0] = fmaf(vr, v.x, acc[4 * q + 0]);
      acc[4 * q + 1] = fmaf(vr, v.y, acc[4 * q + 1]);
      acc[4 * q + 2] = fmaf(vr, v.z, acc[4 * q + 2]);
      acc[4 * q + 3] = fmaf(vr, v.w, acc[4 * q + 3]);
    }
  }

  float pred = b2s;
#pragma unroll
  for (int h = 0; h < 32; h++) {
    const float hv = fmaxf(acc[h] + b1s[h], 0.0f);
    pred = fmaf(hv, W2s[h], pred);
  }
  out[sid] = pred;
}

// ---------------------------------------------------------------------------
// Fallback (only if d_ws is too small): fully fused naive version.
// ---------------------------------------------------------------------------
__global__ __launch_bounds__(256) void tof_fused(
    const float* __restrict__ recordings, const float* __restrict__ sloc,
    const float* __restrict__ emit, const float* __restrict__ rloc,
    const float* __restrict__ W1, const float* __restrict__ b1v,
    const float* __restrict__ W2, const float* __restrict__ b2v,
    float* __restrict__ out) {
  __shared__ float vy[8];
  __shared__ float em[3];
  __shared__ float rl[24];
  __shared__ float b1s[32];
  __shared__ float W2s[32];
  __shared__ float b2s;
  const int t = threadIdx.x;
  const int sid = blockIdx.x * 256 + t;
  const int b = sid >> 14;

  if (t < 8) {
    const float* rp = recordings + ((b << 3) + t) * 4096;
    vy[t] = 0.5f * (rp[2047] + rp[2048]);
  }
  if (t < 3) em[t] = emit[t];
  if (t >= 32 && t < 56) rl[t - 32] = rloc[t - 32];
  if (t >= 64 && t < 96) b1s[t - 64] = b1v[t - 64];
  if (t >= 96 && t < 128) W2s[t - 96] = W2[t - 96];
  if (t == 128) b2s = b2v[0];
  __syncthreads();

  const float x = sloc[sid * 3 + 0];
  const float y = sloc[sid * 3 + 1];
  const float z = sloc[sid * 3 + 2];
  const float ex = x - em[0], ey = y - em[1], ez = z - em[2];
  const float de = sqrtf(ex * ex + ey * ey + ez * ez);

  float acc[32];
#pragma unroll
  for (int h = 0; h < 32; h++) acc[h] = 0.f;

  for (int r = 0; r < 8; r++) {
    const float rx = x - rl[r * 3 + 0];
    const float ry = y - rl[r * 3 + 1];
    const float rz = z - rl[r * 3 + 2];
    const float dr = sqrtf(rx * rx + ry * ry + rz * rz);
    const float ts = rintf(((de + dr) / 343.0f) * 96000.0f);
    const float g0 = ts * (1.0f / 2048.0f) - (1.0f + 64.0f / 2048.0f);
    const float vr = vy[r];
    for (int k = 0; k < 128; k++) {
      const float gx = g0 + (float)k * (1.0f / 8192.0f);
      const float w = fmaxf(0.0f, fmaf(-0.5f, fabsf(gx), 1.0f));
      const float c = w * vr;
      const float* wrow = W1 + (((r << 7) + k) << 5);
#pragma unroll
      for (int h = 0; h < 32; h++) acc[h] = fmaf(c, wrow[h], acc[h]);
    }
  }

  float pred = b2s;
#pragma unroll
  for (int h = 0; h < 32; h++) {
    const float hv = fmaxf(acc[h] + b1s[h], 0.0f);
    pred = fmaf(hv, W2s[h], pred);
  }
  out[sid] = pred;
}

extern "C" void kernel_launch(void* const* d_in, const int* in_sizes, int n_in,
                              void* d_out, int out_size, void* d_ws,
                              size_t ws_size, hipStream_t stream) {
  const float* recordings = (const float*)d_in[0];
  const float* sloc       = (const float*)d_in[1];
  const float* emit       = (const float*)d_in[2];
  const float* rloc       = (const float*)d_in[3];
  const float* W1         = (const float*)d_in[4];
  const float* b1v        = (const float*)d_in[5];
  const float* W2         = (const float*)d_in[6];
  const float* b2v        = (const float*)d_in[7];
  float* out = (float*)d_out;

  const size_t s_bytes = (size_t)TMAX * 8 * 32 * sizeof(float);
  if (ws_size >= s_bytes) {
    float* S = (float*)d_ws;
    dim3 g1(TMAX / 64, 8);
    build_S<<<g1, 256, 0, stream>>>(W1, S);
    tof_main<<<256, 256, 0, stream>>>(recordings, sloc, emit, rloc, b1v, W2,
                                      b2v, S, out);
  } else {
    tof_fused<<<256, 256, 0, stream>>>(recordings, sloc, emit, rloc, W1, b1v,
                                       W2, b2v, out);
  }
}

// Round 2
// 82.152 us; speedup vs baseline: 1.1567x; 1.1567x over previous
//
#include <hip/hip_runtime.h>
#include <math.h>

// Prefix tables in d_ws: P[j][r][h], Q[j][r][h], j in [0,128], r in [0,8), h in [0,32)
//   P[j] = sum_{k<j} W1[(r*128+k)*32+h]
//   Q[j] = sum_{k<j} (k/16384) * W1[(r*128+k)*32+h]
// S[T,r,h] (the W1 row pre-contracted with the triangle weights) is then:
//   S = (1+0.5*g0)*P[ka] + Q[ka] + (1-0.5*g0)*(P[kb]-P[ka]) - (Q[kb]-Q[ka])
// with exact-integer boundaries ka = clamp(8448-4T,0,128), kb = clamp(24832-4T,0,128).
// Fast paths: T<=2080  -> S = (1+0.5g0)*P[128] + Q[128]
//             2112<=T<=6176 -> S = (1-0.5g0)*P[128] - Q[128]
#define PQ_STRIDE (129 * 256)

// ---------------------------------------------------------------------------
// prep: build the prefix tables. 4 blocks x 256 threads, block handles 2 r's.
// ---------------------------------------------------------------------------
__global__ __launch_bounds__(256) void prep(const float* __restrict__ W1,
                                            float* __restrict__ P,
                                            float* __restrict__ Q) {
  __shared__ float slab[2 * 128 * 32];  // [r_local][k][h]
  const int t = threadIdx.x;
  const int r0 = blockIdx.x * 2;
  const float4* src = (const float4*)(W1 + r0 * 128 * 32);
  float4* dst = (float4*)slab;
#pragma unroll
  for (int i = 0; i < 8; i++) dst[t + i * 256] = src[t + i * 256];
  __syncthreads();
  if (t < 64) {
    const int rl = t >> 5, h = t & 31;
    const int r = r0 + rl;
    float p = 0.f, q = 0.f;
    for (int k = 0; k < 128; k++) {
      P[k * 256 + r * 32 + h] = p;
      Q[k * 256 + r * 32 + h] = q;
      const float w = slab[(rl * 128 + k) * 32 + h];
      p += w;
      q = fmaf((float)k * (1.0f / 16384.0f), w, q);
    }
    P[128 * 256 + r * 32 + h] = p;
    Q[128 * 256 + r * 32 + h] = q;
  }
}

// ---------------------------------------------------------------------------
// main: one thread per (b, s). Pure-region closed form; rare prefix lookups.
// ---------------------------------------------------------------------------
__global__ __launch_bounds__(256) void tof_main(
    const float* __restrict__ recordings, const float* __restrict__ sloc,
    const float* __restrict__ emit, const float* __restrict__ rloc,
    const float* __restrict__ b1v, const float* __restrict__ W2,
    const float* __restrict__ b2v, const float* __restrict__ Pg,
    const float* __restrict__ Qg, float* __restrict__ out) {
  __shared__ __align__(16) float Ps[256];   // P[128][r][h]
  __shared__ __align__(16) float Qs[256];   // Q[128][r][h]
  __shared__ __align__(16) float b1s[32];
  __shared__ __align__(16) float W2s[32];
  __shared__ float vys[8];
  __shared__ float ems[3];
  __shared__ float rls[24];
  __shared__ float b2s;
  const int t = threadIdx.x;
  const int sid = blockIdx.x * 256 + t;
  const int b = sid >> 14;  // 64 blocks per b -> uniform within block

  if (t < 64) {
    ((float4*)Ps)[t] = ((const float4*)(Pg + 128 * 256))[t];
  } else if (t < 128) {
    ((float4*)Qs)[t - 64] = ((const float4*)(Qg + 128 * 256))[t - 64];
  } else if (t < 152) {
    rls[t - 128] = rloc[t - 128];
  } else if (t < 155) {
    ems[t - 152] = emit[t - 152];
  } else if (t == 155) {
    b2s = b2v[0];
  } else if (t >= 160 && t < 168) {
    const int r = t - 160;
    const float* rp = recordings + ((b << 3) + r) * 4096;
    vys[r] = 0.5f * (rp[2047] + rp[2048]);
  } else if (t >= 192 && t < 224) {
    b1s[t - 192] = b1v[t - 192];
  } else if (t >= 224) {
    W2s[t - 224] = W2[t - 224];
  }
  __syncthreads();

  const float xx = sloc[3 * sid + 0];
  const float yy = sloc[3 * sid + 1];
  const float zz = sloc[3 * sid + 2];
  const float ex = xx - ems[0], ey = yy - ems[1], ez = zz - ems[2];
  const float de = sqrtf(ex * ex + ey * ey + ez * ez);

  float4 acc[8];
#pragma unroll
  for (int q = 0; q < 8; q++) acc[q] = make_float4(0.f, 0.f, 0.f, 0.f);

#pragma unroll
  for (int r = 0; r < 8; r++) {
    const float rx = xx - rls[3 * r + 0];
    const float ry = yy - rls[3 * r + 1];
    const float rz = zz - rls[3 * r + 2];
    const float dr = sqrtf(rx * rx + ry * ry + rz * rz);
    const float ts = rintf(((de + dr) / 343.0f) * 96000.0f);
    const int T = (int)ts;
    const float g0 = (ts - 64.0f) * (1.0f / 2048.0f) - 1.0f;
    const float vr = vys[r];
    const bool fast1 = (T <= 2080);
    const bool fast3 = (T >= 2112) && (T <= 6176);
    if (fast1 | fast3) {
      const float sg = fast1 ? 1.0f : -1.0f;
      const float aa = vr * fmaf(0.5f * sg, g0, 1.0f);
      const float cc = sg * vr;
      const float4* Pr = (const float4*)(Ps + r * 32);
      const float4* Qr = (const float4*)(Qs + r * 32);
#pragma unroll
      for (int q = 0; q < 8; q++) {
        const float4 pv = Pr[q];
        const float4 qv = Qr[q];
        acc[q].x = fmaf(aa, pv.x, fmaf(cc, qv.x, acc[q].x));
        acc[q].y = fmaf(aa, pv.y, fmaf(cc, qv.y, acc[q].y));
        acc[q].z = fmaf(aa, pv.z, fmaf(cc, qv.z, acc[q].z));
        acc[q].w = fmaf(aa, pv.w, fmaf(cc, qv.w, acc[q].w));
      }
    } else {
      // rare: T in [2081,2111] (kink inside window) or T >= 6177 (support edge)
      int ka = 8448 - 4 * T;  ka = min(max(ka, 0), 128);
      int kb = 24832 - 4 * T; kb = min(max(kb, 0), 128);
      const float u = fmaf(0.5f, g0, 1.0f);    // 1 + 0.5*g0
      const float v = fmaf(-0.5f, g0, 1.0f);   // 1 - 0.5*g0
      const float4* Pa = (const float4*)(Pg + ka * 256 + r * 32);
      const float4* Qa = (const float4*)(Qg + ka * 256 + r * 32);
      const float4* Pb = (const float4*)(Pg + kb * 256 + r * 32);
      const float4* Qb = (const float4*)(Qg + kb * 256 + r * 32);
#pragma unroll
      for (int q = 0; q < 8; q++) {
        const float4 pa = Pa[q], qa = Qa[q], pb = Pb[q], qb = Qb[q];
        const float s0 = u * pa.x + qa.x + v * (pb.x - pa.x) - (qb.x - qa.x);
        const float s1 = u * pa.y + qa.y + v * (pb.y - pa.y) - (qb.y - qa.y);
        const float s2 = u * pa.z + qa.z + v * (pb.z - pa.z) - (qb.z - qa.z);
        const float s3 = u * pa.w + qa.w + v * (pb.w - pa.w) - (qb.w - qa.w);
        acc[q].x = fmaf(vr, s0, acc[q].x);
        acc[q].y = fmaf(vr, s1, acc[q].y);
        acc[q].z = fmaf(vr, s2, acc[q].z);
        acc[q].w = fmaf(vr, s3, acc[q].w);
      }
    }
  }

  float pred = b2s;
  const float4* b14 = (const float4*)b1s;
  const float4* W24 = (const float4*)W2s;
#pragma unroll
  for (int q = 0; q < 8; q++) {
    const float4 hb = b14[q];
    const float4 wv = W24[q];
    pred = fmaf(fmaxf(acc[q].x + hb.x, 0.0f), wv.x, pred);
    pred = fmaf(fmaxf(acc[q].y + hb.y, 0.0f), wv.y, pred);
    pred = fmaf(fmaxf(acc[q].z + hb.z, 0.0f), wv.z, pred);
    pred = fmaf(fmaxf(acc[q].w + hb.w, 0.0f), wv.w, pred);
  }
  out[sid] = pred;
}

// ---------------------------------------------------------------------------
// Fallback (only if d_ws is too small): fully fused naive version.
// ---------------------------------------------------------------------------
__global__ __launch_bounds__(256) void tof_fused(
    const float* __restrict__ recordings, const float* __restrict__ sloc,
    const float* __restrict__ emit, const float* __restrict__ rloc,
    const float* __restrict__ W1, const float* __restrict__ b1v,
    const float* __restrict__ W2, const float* __restrict__ b2v,
    float* __restrict__ out) {
  __shared__ float vy[8];
  __shared__ float em[3];
  __shared__ float rl[24];
  __shared__ float b1s[32];
  __shared__ float W2s[32];
  __shared__ float b2s;
  const int t = threadIdx.x;
  const int sid = blockIdx.x * 256 + t;
  const int b = sid >> 14;

  if (t < 8) {
    const float* rp = recordings + ((b << 3) + t) * 4096;
    vy[t] = 0.5f * (rp[2047] + rp[2048]);
  }
  if (t < 3) em[t] = emit[t];
  if (t >= 32 && t < 56) rl[t - 32] = rloc[t - 32];
  if (t >= 64 && t < 96) b1s[t - 64] = b1v[t - 64];
  if (t >= 96 && t < 128) W2s[t - 96] = W2[t - 96];
  if (t == 128) b2s = b2v[0];
  __syncthreads();

  const float x = sloc[sid * 3 + 0];
  const float y = sloc[sid * 3 + 1];
  const float z = sloc[sid * 3 + 2];
  const float ex = x - em[0], ey = y - em[1], ez = z - em[2];
  const float de = sqrtf(ex * ex + ey * ey + ez * ez);

  float acc[32];
#pragma unroll
  for (int h = 0; h < 32; h++) acc[h] = 0.f;

  for (int r = 0; r < 8; r++) {
    const float rx = x - rl[r * 3 + 0];
    const float ry = y - rl[r * 3 + 1];
    const float rz = z - rl[r * 3 + 2];
    const float dr = sqrtf(rx * rx + ry * ry + rz * rz);
    const float ts = rintf(((de + dr) / 343.0f) * 96000.0f);
    const float g0 = ts * (1.0f / 2048.0f) - (1.0f + 64.0f / 2048.0f);
    const float vr = vy[r];
    for (int k = 0; k < 128; k++) {
      const float gx = g0 + (float)k * (1.0f / 8192.0f);
      const float w = fmaxf(0.0f, fmaf(-0.5f, fabsf(gx), 1.0f));
      const float c = w * vr;
      const float* wrow = W1 + (((r << 7) + k) << 5);
#pragma unroll
      for (int h = 0; h < 32; h++) acc[h] = fmaf(c, wrow[h], acc[h]);
    }
  }

  float pred = b2s;
#pragma unroll
  for (int h = 0; h < 32; h++) {
    const float hv = fmaxf(acc[h] + b1s[h], 0.0f);
    pred = fmaf(hv, W2s[h], pred);
  }
  out[sid] = pred;
}

extern "C" void kernel_launch(void* const* d_in, const int* in_sizes, int n_in,
                              void* d_out, int out_size, void* d_ws,
                              size_t ws_size, hipStream_t stream) {
  const float* recordings = (const float*)d_in[0];
  const float* sloc       = (const float*)d_in[1];
  const float* emit       = (const float*)d_in[2];
  const float* rloc       = (const float*)d_in[3];
  const float* W1         = (const float*)d_in[4];
  const float* b1v        = (const float*)d_in[5];
  const float* W2         = (const float*)d_in[6];
  const float* b2v        = (const float*)d_in[7];
  float* out = (float*)d_out;

  const size_t pq_bytes = (size_t)2 * PQ_STRIDE * sizeof(float);
  if (ws_size >= pq_bytes) {
    float* P = (float*)d_ws;
    float* Q = P + PQ_STRIDE;
    prep<<<4, 256, 0, stream>>>(W1, P, Q);
    tof_main<<<256, 256, 0, stream>>>(recordings, sloc, emit, rloc, b1v, W2,
                                      b2v, P, Q, out);
  } else {
    tof_fused<<<256, 256, 0, stream>>>(recordings, sloc, emit, rloc, W1, b1v,
                                       W2, b2v, out);
  }
}